// Round 3
// baseline (551.254 us; speedup 1.0000x reference)
//
#include <hip/hip_runtime.h>
#include <hip/hip_fp16.h>

typedef _Float16 f16;
typedef _Float16 f16x2 __attribute__((ext_vector_type(2)));
typedef _Float16 f16x8 __attribute__((ext_vector_type(8)));
typedef float    f32x4 __attribute__((ext_vector_type(4)));

#define NB   8192
#define TOUT 10
#define LMAX 12
#define EMB  300

__device__ __forceinline__ float sigm_(float x) {
    return __builtin_amdgcn_rcpf(1.0f + __builtin_amdgcn_exp2f(x * -1.44269504f));
}
__device__ __forceinline__ float tanh_(float x) {
    return 1.0f - 2.0f * __builtin_amdgcn_rcpf(1.0f + __builtin_amdgcn_exp2f(x * 2.88539008f));
}

// async global->LDS, 16B per lane. LDS dest is wave-uniform base + lane*16.
__device__ __forceinline__ void gl_lds16(const f16* g, f16* l) {
    __builtin_amdgcn_global_load_lds(
        (const __attribute__((address_space(1))) void*)g,
        (__attribute__((address_space(3))) void*)l, 16, 0, 0);
}

#define WAITV(n) asm volatile("s_waitcnt vmcnt(" #n ")" ::: "memory")

// ---------------------------------------------------------------------------
// K0a: pack LSTM weights into MFMA B-fragment tiles, f16, gate-permuted cols.
// Dest per dir: [kc 0..15][ntile 0..63][512 f16]; within tile element (k,n):
// offset = ((k%32)/8*16 + n%16)*8 + k%8 (lane l reads l*8..l*8+7).
// Column permutation (16-wave / 64-col-per-wave gate split):
//   n -> w2 = n/64 (wave), gate = (n>>4)&3, unit u = w2*16 + (n&15)
// ---------------------------------------------------------------------------
__global__ __launch_bounds__(256) void pack_w2(
    const float* __restrict__ wih_f, const float* __restrict__ whh_f,
    const float* __restrict__ wih_b, const float* __restrict__ whh_b,
    f16* __restrict__ Wp) {
    int idx = blockIdx.x * 256 + threadIdx.x;   // 0 .. 2*524288-1
    int d   = idx >> 19;
    int r   = idx & 524287;
    int tile = r >> 9;
    int e    = r & 511;
    int kc = tile >> 6, nt = tile & 63;
    int khi = e >> 7, rem = e & 127, nl = rem >> 3, klo = rem & 7;
    int n = nt * 16 + nl;
    int k = kc * 32 + khi * 8 + klo;
    int gate = (n >> 4) & 3;
    int u = ((n >> 6) << 4) | (n & 15);
    int srow = gate * 256 + u;
    const float* wih = d ? wih_b : wih_f;
    const float* whh = d ? whh_b : whh_f;
    float v = (k < 256) ? wih[srow * 256 + k] : whh[srow * 256 + (k - 256)];
    Wp[idx] = (f16)v;
}

__global__ __launch_bounds__(256) void pack_bias(
    const float* __restrict__ bih_f, const float* __restrict__ bhh_f,
    const float* __restrict__ bih_b, const float* __restrict__ bhh_b,
    float* __restrict__ bp) {
    int idx = blockIdx.x * 256 + threadIdx.x;   // 2048
    int d = idx >> 10, n = idx & 1023;
    int gate = (n >> 4) & 3;
    int u = ((n >> 6) << 4) | (n & 15);
    int srow = gate * 256 + u;
    bp[idx] = d ? (bih_b[srow] + bhh_b[srow]) : (bih_f[srow] + bhh_f[srow]);
}

// K0b: pack out_w (512x512) into B-fragment tiles: [kc 0..15][ntile 0..31][512]
__global__ __launch_bounds__(256) void pack_w3(
    const float* __restrict__ out_w, f16* __restrict__ W3p) {
    int idx = blockIdx.x * 256 + threadIdx.x;   // 262144
    int tile = idx >> 9, e = idx & 511;
    int kc = tile >> 5, nt = tile & 31;
    int khi = e >> 7, rem = e & 127, nl = rem >> 3, klo = rem & 7;
    int n = nt * 16 + nl, k = kc * 32 + khi * 8 + klo;
    W3p[idx] = (f16)out_w[n * 512 + k];
}

// K0c: P[36][256] = emb_table @ enc_w^T + enc_b (fp32)
__global__ __launch_bounds__(256) void enc_proj(
    const float* __restrict__ tab, const float* __restrict__ ew,
    const float* __restrict__ eb, float* __restrict__ P) {
    int v = blockIdx.x, j = threadIdx.x;
    const float* a = tab + v * EMB;
    const float* w = ew + j * EMB;
    float s = 0.0f;
    for (int k = 0; k < EMB; ++k) s += a[k] * w[k];
    P[v * 256 + j] = s + eb[j];
}

// ---------------------------------------------------------------------------
// K1: build seq in MFMA A-fragment tile layout, f16.
// seqp: [t 0..9][mtile 0..511][kc 0..7][512 f16]; element (row,k):
// offset = ((k%32)/8*16 + row%16)*8 + k%8
// ---------------------------------------------------------------------------
__global__ __launch_bounds__(256) void build_seq(
    const int* __restrict__ words, const int* __restrict__ lengths,
    const float* __restrict__ P, f16* __restrict__ seqp) {
    int gi = blockIdx.x * 256 + threadIdx.x;    // 2,621,440 total
    int bl  = gi & 15;
    int khi = (gi >> 4) & 3;
    int kc  = (gi >> 6) & 7;
    int mt  = (gi >> 9) & 511;
    int t   = gi >> 18;
    int b = mt * 16 + bl;
    int L = lengths[b];
    float pos = ((float)t * (float)(L - 1)) / 9.0f;
    int i0 = (int)pos;
    float f = pos - (float)i0;
    int i1 = min(i0 + 1, L - 1);
    int c0 = words[b * LMAX + i0];
    int c1 = words[b * LMAX + i1];
    const float* p0 = P + c0 * 256 + kc * 32 + khi * 8;
    const float* p1 = P + c1 * 256 + kc * 32 + khi * 8;
    f16x8 r;
#pragma unroll
    for (int j = 0; j < 8; ++j) {
        float v = p0[j] * (1.0f - f) + p1[j] * f;
        v = fmaxf(v, 0.0f);
        r[j] = (f16)v;
    }
    *((f16x8*)seqp + gi) = r;
}

// ---------------------------------------------------------------------------
// K2: fused BiLSTM. 256 blocks (128 fwd + 128 bwd) x 1024 thr (16 waves),
// 1 block/CU, 4 waves/SIMD. 64 arch VGPR + 64 AGPR acc = the hard 128 cap:
// no register headroom exists, so the weight stream is software-pipelined
// through the LDS-DMA queue (global_load_lds, depth-3 1KB ring per wave)
// with COUNTED vmcnt waits (never 0 mid-loop). This breaks the round-2
// phase-locked convoy (load-all/wait-all/mfma-all, MfmaUtil 47%): each
// wave now has tile i in regs, i+1 landed, i+2/i+3 in flight.
// Consumption order: h-half (kc 8..15) first, then seq-half, so the
// step's seq tile (single 32 KB buffer, DMA'd at step start, FIRST in the
// vmcnt FIFO) lands long before it is read. LDS = 48 KB wring + 64 KB
// hbuf + 32 KB sbuf = 144 KB.
// ---------------------------------------------------------------------------
__global__ __launch_bounds__(1024) void lstm_fused(
    const f16* __restrict__ seqp, const f16* __restrict__ Wp,
    const float* __restrict__ bp, f16* __restrict__ hcat) {
    const int dir  = blockIdx.x >> 7;
    const int r0t  = (blockIdx.x & 127) << 2;   // row-tile base, 4 tiles of 16
    const int wave = threadIdx.x >> 6;          // 0..15
    const int lane = threadIdx.x & 63;
    const int l16  = lane & 15;
    const int quad = lane >> 4;

    __shared__ __align__(16) f16 hbuf[2][16384];   // 2 x 32 KB  h state
    __shared__ __align__(16) f16 sbuf[16384];      // 32 KB      seq tile
    __shared__ __align__(16) f16 wbuf[24576];      // 48 KB      16w x 3 x 1KB

    // zero h0 buffer
    {
        f16x8 z = {(f16)0, (f16)0, (f16)0, (f16)0, (f16)0, (f16)0, (f16)0, (f16)0};
        for (int i = threadIdx.x; i < 2048; i += 1024) ((f16x8*)hbuf[0])[i] = z;
    }

    // per-lane gate biases: wave owns cols [wave*64, wave*64+64); nt = gate
    const float* bpd = bp + dir * 1024 + wave * 64;
    float bias_l[4];
#pragma unroll
    for (int nt = 0; nt < 4; ++nt) bias_l[nt] = bpd[nt * 16 + l16];

    // weight stream bases. consumption index j 0..15 maps to packed kc = j^8
    // (h-half kc 8..15 first). tile(j,nt) src = wsrc + (j^8)*32768 + nt*512.
    const f16* wsrc = Wp + dir * 524288 + wave * 2048 + lane * 8;  // per-lane
    f16*       wdst = wbuf + wave * 1536;                          // uniform
    const f16* wred = wdst + lane * 8;                             // per-lane

    // this lane's h-unit: u = wave*16 + l16  (one unit per lane)
    const int slot = wave >> 1;                  // k-chunk 0..7 within dir
    const int ofs0 = (((wave & 1) * 2 + (l16 >> 3)) * 16 + quad * 4) * 8 + (l16 & 7);
    const int tile_lo = (r0t * 16 + dir * 8 + slot) * 512;

    float cst[4][4];
#pragma unroll
    for (int m = 0; m < 4; ++m)
#pragma unroll
        for (int q = 0; q < 4; ++q) cst[m][q] = 0.0f;

    __syncthreads();

    int cur = 0;
#pragma unroll 1
    for (int step = 0; step < TOUT; ++step) {
        const int t = dir ? (9 - step) : step;

        const f16* sb   = &sbuf[lane * 8];
        const f16* hb_r = &hbuf[cur][lane * 8];
        f16*       hb_w = hbuf[cur ^ 1];

        // seq tile DMA for THIS step -- issued first (head of vmcnt FIFO,
        // retires before any weight tile we wait on; consumed from j=8).
        {
            const f16* ss = seqp + (size_t)(t * 512 + r0t) * 4096;
            gl_lds16(ss + threadIdx.x * 8,        &sbuf[wave * 512]);
            gl_lds16(ss + 8192 + threadIdx.x * 8, &sbuf[8192 + wave * 512]);
        }
        // weight ring prologue: tiles (j=0,nt=0..2) -> slots 0,1,2
        gl_lds16(wsrc + 8 * 32768 + 0 * 512, wdst + 0 * 512);
        gl_lds16(wsrc + 8 * 32768 + 1 * 512, wdst + 1 * 512);
        gl_lds16(wsrc + 8 * 32768 + 2 * 512, wdst + 2 * 512);

        f32x4 acc[4][4];
#pragma unroll
        for (int m = 0; m < 4; ++m)
#pragma unroll
            for (int nt = 0; nt < 4; ++nt)
#pragma unroll
                for (int q = 0; q < 4; ++q) acc[m][nt][q] = bias_l[nt];

        // ---- main pipeline: j = 0..14 (h-half first via kc=j^8) ----
        int jm = 0;   // j % 3
#pragma unroll 1
        for (int j = 0; j < 15; ++j) {
            // afrag source: j<8 -> hbuf (kcl=j); j>=8 -> sbuf (kc=j-8)
            const f16* ab = (j < 8) ? hb_r : (sb - 4096);
            f16x8 afrag[4];
#pragma unroll
            for (int m = 0; m < 4; ++m)
                afrag[m] = *(const f16x8*)(ab + (m * 8 + j) * 512);

            int s0 = jm;
            int s1 = jm + 1; if (s1 >= 3) s1 -= 3;
            int s2 = jm + 2; if (s2 >= 3) s2 -= 3;
            const f16* wn0 = wsrc + ((j      ^ 8) * 32768);
            const f16* wn1 = wsrc + (((j + 1) ^ 8) * 32768);

            // nt = 0 : consume slot s0, issue tile (j,3) -> s0
            WAITV(2);
            {
                f16x8 b = *(const f16x8*)(wred + s0 * 512);
                __builtin_amdgcn_s_setprio(1);
#pragma unroll
                for (int m = 0; m < 4; ++m)
                    acc[m][0] = __builtin_amdgcn_mfma_f32_16x16x32_f16(afrag[m], b, acc[m][0], 0, 0, 0);
                __builtin_amdgcn_s_setprio(0);
                gl_lds16(wn0 + 3 * 512, wdst + s0 * 512);
            }
            // nt = 1 : consume s1, issue (j+1,0) -> s1
            WAITV(2);
            {
                f16x8 b = *(const f16x8*)(wred + s1 * 512);
                __builtin_amdgcn_s_setprio(1);
#pragma unroll
                for (int m = 0; m < 4; ++m)
                    acc[m][1] = __builtin_amdgcn_mfma_f32_16x16x32_f16(afrag[m], b, acc[m][1], 0, 0, 0);
                __builtin_amdgcn_s_setprio(0);
                gl_lds16(wn1 + 0 * 512, wdst + s1 * 512);
            }
            // nt = 2 : consume s2, issue (j+1,1) -> s2
            WAITV(2);
            {
                f16x8 b = *(const f16x8*)(wred + s2 * 512);
                __builtin_amdgcn_s_setprio(1);
#pragma unroll
                for (int m = 0; m < 4; ++m)
                    acc[m][2] = __builtin_amdgcn_mfma_f32_16x16x32_f16(afrag[m], b, acc[m][2], 0, 0, 0);
                __builtin_amdgcn_s_setprio(0);
                gl_lds16(wn1 + 1 * 512, wdst + s2 * 512);
            }
            // nt = 3 : consume s0 (tile (j,3)), issue (j+1,2) -> s0
            WAITV(2);
            {
                f16x8 b = *(const f16x8*)(wred + s0 * 512);
                __builtin_amdgcn_s_setprio(1);
#pragma unroll
                for (int m = 0; m < 4; ++m)
                    acc[m][3] = __builtin_amdgcn_mfma_f32_16x16x32_f16(afrag[m], b, acc[m][3], 0, 0, 0);
                __builtin_amdgcn_s_setprio(0);
                gl_lds16(wn1 + 2 * 512, wdst + s0 * 512);
            }
            jm = (jm == 2) ? 0 : jm + 1;
        }

        // ---- peeled j = 15 (kc=7, seq half); jm = 0 here ----
        {
            const f16* ab = sb - 4096;
            f16x8 afrag[4];
#pragma unroll
            for (int m = 0; m < 4; ++m)
                afrag[m] = *(const f16x8*)(ab + (m * 8 + 15) * 512);
            const f16* wn0 = wsrc + 7 * 32768;   // (15^8)=7

            WAITV(2);   // c60 done
            {
                f16x8 b = *(const f16x8*)(wred + 0 * 512);
                __builtin_amdgcn_s_setprio(1);
#pragma unroll
                for (int m = 0; m < 4; ++m)
                    acc[m][0] = __builtin_amdgcn_mfma_f32_16x16x32_f16(afrag[m], b, acc[m][0], 0, 0, 0);
                __builtin_amdgcn_s_setprio(0);
                gl_lds16(wn0 + 3 * 512, wdst + 0 * 512);   // c63 -> slot 0
            }
            WAITV(2);   // c61 done (c62,c63 may fly)
            {
                f16x8 b = *(const f16x8*)(wred + 1 * 512);
                __builtin_amdgcn_s_setprio(1);
#pragma unroll
                for (int m = 0; m < 4; ++m)
                    acc[m][1] = __builtin_amdgcn_mfma_f32_16x16x32_f16(afrag[m], b, acc[m][1], 0, 0, 0);
                __builtin_amdgcn_s_setprio(0);
            }
            WAITV(1);   // c62 done
            {
                f16x8 b = *(const f16x8*)(wred + 2 * 512);
                __builtin_amdgcn_s_setprio(1);
#pragma unroll
                for (int m = 0; m < 4; ++m)
                    acc[m][2] = __builtin_amdgcn_mfma_f32_16x16x32_f16(afrag[m], b, acc[m][2], 0, 0, 0);
                __builtin_amdgcn_s_setprio(0);
            }
            WAITV(0);   // c63 done
            {
                f16x8 b = *(const f16x8*)(wred + 0 * 512);
                __builtin_amdgcn_s_setprio(1);
#pragma unroll
                for (int m = 0; m < 4; ++m)
                    acc[m][3] = __builtin_amdgcn_mfma_f32_16x16x32_f16(afrag[m], b, acc[m][3], 0, 0, 0);
                __builtin_amdgcn_s_setprio(0);
            }
        }

        // lane-local gate combine; h -> LDS (for recurrence) + global hcat.
        // acc[m][nt][q]: row = m*16 + quad*4 + q, gate = nt, unit = wave*16+l16
        f16* hct = hcat + ((size_t)t * 4194304 + tile_lo);
#pragma unroll
        for (int m = 0; m < 4; ++m) {
#pragma unroll
            for (int q = 0; q < 4; ++q) {
                float iv = acc[m][0][q];
                float fv = acc[m][1][q];
                float gv = acc[m][2][q];
                float ov = acc[m][3][q];
                float c = sigm_(fv) * cst[m][q] + sigm_(iv) * tanh_(gv);
                cst[m][q] = c;
                f16 hv = (f16)(sigm_(ov) * tanh_(c));
                int wt = ofs0 + q * 8;
                hb_w[(m * 8 + slot) * 512 + wt] = hv;
                hct[m * 8192 + wt] = hv;
            }
        }

        __syncthreads();   // single barrier per step; drains all vmcnt
        cur ^= 1;
    }
}

// ---------------------------------------------------------------------------
// K3: out = h_cat(81920x512 f16, frag layout) @ W3p + out_b -> fp32 (B,10,512)
// 1280 blocks x 512 thr; block tile 64 rows x 512 cols; wave: 64x64.
// ---------------------------------------------------------------------------
__global__ __launch_bounds__(512) void out_gemm(
    const f16* __restrict__ hcat, const f16* __restrict__ W3p,
    const float* __restrict__ out_b, float* __restrict__ out) {
    const int mt0  = blockIdx.x << 2;
    const int wave = threadIdx.x >> 6;
    const int lane = threadIdx.x & 63;
    const int l16  = lane & 15;
    const int quad = lane >> 4;
    const int n0   = wave * 64;

    float bias_l[4];
#pragma unroll
    for (int nt = 0; nt < 4; ++nt) bias_l[nt] = out_b[n0 + nt * 16 + l16];

    f32x4 acc[4][4];
#pragma unroll
    for (int m = 0; m < 4; ++m)
#pragma unroll
        for (int nt = 0; nt < 4; ++nt)
#pragma unroll
            for (int q = 0; q < 4; ++q) acc[m][nt][q] = bias_l[nt];

#pragma unroll 2
    for (int kc = 0; kc < 16; ++kc) {
        f16x8 a[4], b[4];
#pragma unroll
        for (int m = 0; m < 4; ++m)
            a[m] = *(const f16x8*)(hcat + ((size_t)((mt0 + m) * 16 + kc) * 512 + lane * 8));
#pragma unroll
        for (int nt = 0; nt < 4; ++nt)
            b[nt] = *(const f16x8*)(W3p + ((kc * 32 + wave * 4 + nt) * 512 + lane * 8));
#pragma unroll
        for (int m = 0; m < 4; ++m)
#pragma unroll
            for (int nt = 0; nt < 4; ++nt)
                acc[m][nt] = __builtin_amdgcn_mfma_f32_16x16x32_f16(a[m], b[nt], acc[m][nt], 0, 0, 0);
    }

#pragma unroll
    for (int m = 0; m < 4; ++m) {
#pragma unroll
        for (int nt = 0; nt < 4; ++nt) {
#pragma unroll
            for (int q = 0; q < 4; ++q) {
                int R = mt0 * 16 + m * 16 + quad * 4 + q;
                int t = R >> 13;
                int b = R & 8191;
                out[(size_t)(b * 10 + t) * 512 + n0 + nt * 16 + l16] = acc[m][nt][q];
            }
        }
    }
}

// ---------------------------------------------------------------------------
extern "C" void kernel_launch(void* const* d_in, const int* in_sizes, int n_in,
                              void* d_out, int out_size, void* d_ws, size_t ws_size,
                              hipStream_t stream) {
    const int*   words   = (const int*)d_in[0];
    const int*   lengths = (const int*)d_in[1];
    const float* tab     = (const float*)d_in[2];
    const float* enc_w   = (const float*)d_in[3];
    const float* enc_b   = (const float*)d_in[4];
    const float* wih_f   = (const float*)d_in[5];
    const float* whh_f   = (const float*)d_in[6];
    const float* bih_f   = (const float*)d_in[7];
    const float* bhh_f   = (const float*)d_in[8];
    const float* wih_b   = (const float*)d_in[9];
    const float* whh_b   = (const float*)d_in[10];
    const float* bih_b   = (const float*)d_in[11];
    const float* bhh_b   = (const float*)d_in[12];
    const float* out_w   = (const float*)d_in[13];
    const float* out_b   = (const float*)d_in[14];
    float* out = (float*)d_out;

    char* ws = (char*)d_ws;
    f16*   Wp   = (f16*)(ws + 0);           //  2 MB
    f16*   W3p  = (f16*)(ws + 2097152);     //  0.5 MB
    float* bp   = (float*)(ws + 2621440);   //  8 KB
    float* P    = (float*)(ws + 2629632);   //  36 KB
    f16*   seqp = (f16*)(ws + 2666496);     //  40 MB
    f16*   hcat = (f16*)(ws + 44609536);    //  80 MB  (total ~122.6 MB)

    pack_w2<<<4096, 256, 0, stream>>>(wih_f, whh_f, wih_b, whh_b, Wp);
    pack_bias<<<8, 256, 0, stream>>>(bih_f, bhh_f, bih_b, bhh_b, bp);
    pack_w3<<<1024, 256, 0, stream>>>(out_w, W3p);
    enc_proj<<<36, 256, 0, stream>>>(tab, enc_w, enc_b, P);
    build_seq<<<10240, 256, 0, stream>>>(words, lengths, P, seqp);
    lstm_fused<<<256, 1024, 0, stream>>>(seqp, Wp, bp, hcat);
    out_gemm<<<1280, 512, 0, stream>>>(hcat, W3p, out_b, out);
}

// Round 4
// 477.317 us; speedup vs baseline: 1.1549x; 1.1549x over previous
//
#include <hip/hip_runtime.h>
#include <hip/hip_fp16.h>

typedef _Float16 f16;
typedef _Float16 f16x2 __attribute__((ext_vector_type(2)));
typedef _Float16 f16x8 __attribute__((ext_vector_type(8)));
typedef float    f32x4 __attribute__((ext_vector_type(4)));

#define NB   8192
#define TOUT 10
#define LMAX 12
#define EMB  300

__device__ __forceinline__ float sigm_(float x) {
    return __builtin_amdgcn_rcpf(1.0f + __builtin_amdgcn_exp2f(x * -1.44269504f));
}
__device__ __forceinline__ float tanh_(float x) {
    return 1.0f - 2.0f * __builtin_amdgcn_rcpf(1.0f + __builtin_amdgcn_exp2f(x * 2.88539008f));
}
__device__ __forceinline__ f16x2 pk_f16(float a, float b) {
    return __builtin_bit_cast(f16x2, __builtin_amdgcn_cvt_pkrtz(a, b));
}

// async global->LDS, 16B per lane. LDS dest is wave-uniform base + lane*16.
__device__ __forceinline__ void gl_lds16(const f16* g, f16* l) {
    __builtin_amdgcn_global_load_lds(
        (const __attribute__((address_space(1))) void*)g,
        (__attribute__((address_space(3))) void*)l, 16, 0, 0);
}

// ---------------------------------------------------------------------------
// K0a: pack LSTM weights into MFMA B-fragment tiles, f16, gate-permuted cols.
// Dest per dir: [kc 0..15][ntile 0..63][512 f16]; within tile element (k,n):
// offset = ((k%32)/8*16 + n%16)*8 + k%8 (lane l reads l*8..l*8+7).
// Column permutation (8-wave / 128-col-per-wave, round-0 scheme):
//   n -> w=n/128, rr=n%128, gate=rr>>5, us=(rr>>4)&1, l16=rr&15,
//   unit u = w*32 + 2*l16 + us;  srow = gate*256 + u.
// Wave's 8 n-tiles = 4 gates x 2 unit-subtiles; lane l16 owns units
// (2*l16, 2*l16+1) -> f16x2 h stores in the combine.
// ---------------------------------------------------------------------------
__global__ __launch_bounds__(256) void pack_w2(
    const float* __restrict__ wih_f, const float* __restrict__ whh_f,
    const float* __restrict__ wih_b, const float* __restrict__ whh_b,
    f16* __restrict__ Wp) {
    int idx = blockIdx.x * 256 + threadIdx.x;   // 0 .. 2*524288-1
    int d   = idx >> 19;
    int r   = idx & 524287;
    int tile = r >> 9;
    int e    = r & 511;
    int kc = tile >> 6, nt = tile & 63;
    int khi = e >> 7, rem = e & 127, nl = rem >> 3, klo = rem & 7;
    int n = nt * 16 + nl;
    int k = kc * 32 + khi * 8 + klo;
    int w = n >> 7, rr = n & 127, gate = rr >> 5;
    int u = w * 32 + 2 * (rr & 15) + ((rr >> 4) & 1);
    int srow = gate * 256 + u;
    const float* wih = d ? wih_b : wih_f;
    const float* whh = d ? whh_b : whh_f;
    float v = (k < 256) ? wih[srow * 256 + k] : whh[srow * 256 + (k - 256)];
    Wp[idx] = (f16)v;
}

__global__ __launch_bounds__(256) void pack_bias(
    const float* __restrict__ bih_f, const float* __restrict__ bhh_f,
    const float* __restrict__ bih_b, const float* __restrict__ bhh_b,
    float* __restrict__ bp) {
    int idx = blockIdx.x * 256 + threadIdx.x;   // 2048
    int d = idx >> 10, n = idx & 1023;
    int w = n >> 7, rr = n & 127, gate = rr >> 5;
    int u = w * 32 + 2 * (rr & 15) + ((rr >> 4) & 1);
    int srow = gate * 256 + u;
    bp[idx] = d ? (bih_b[srow] + bhh_b[srow]) : (bih_f[srow] + bhh_f[srow]);
}

// K0b: pack out_w (512x512) into B-fragment tiles: [kc 0..15][ntile 0..31][512]
__global__ __launch_bounds__(256) void pack_w3(
    const float* __restrict__ out_w, f16* __restrict__ W3p) {
    int idx = blockIdx.x * 256 + threadIdx.x;   // 262144
    int tile = idx >> 9, e = idx & 511;
    int kc = tile >> 5, nt = tile & 31;
    int khi = e >> 7, rem = e & 127, nl = rem >> 3, klo = rem & 7;
    int n = nt * 16 + nl, k = kc * 32 + khi * 8 + klo;
    W3p[idx] = (f16)out_w[n * 512 + k];
}

// K0c: P[36][256] = emb_table @ enc_w^T + enc_b (fp32)
__global__ __launch_bounds__(256) void enc_proj(
    const float* __restrict__ tab, const float* __restrict__ ew,
    const float* __restrict__ eb, float* __restrict__ P) {
    int v = blockIdx.x, j = threadIdx.x;
    const float* a = tab + v * EMB;
    const float* w = ew + j * EMB;
    float s = 0.0f;
    for (int k = 0; k < EMB; ++k) s += a[k] * w[k];
    P[v * 256 + j] = s + eb[j];
}

// ---------------------------------------------------------------------------
// K1: build seq in MFMA A-fragment tile layout, f16.
// seqp: [t 0..9][mtile 0..511][kc 0..7][512 f16]; element (row,k):
// offset = ((k%32)/8*16 + row%16)*8 + k%8
// ---------------------------------------------------------------------------
__global__ __launch_bounds__(256) void build_seq(
    const int* __restrict__ words, const int* __restrict__ lengths,
    const float* __restrict__ P, f16* __restrict__ seqp) {
    int gi = blockIdx.x * 256 + threadIdx.x;    // 2,621,440 total
    int bl  = gi & 15;
    int khi = (gi >> 4) & 3;
    int kc  = (gi >> 6) & 7;
    int mt  = (gi >> 9) & 511;
    int t   = gi >> 18;
    int b = mt * 16 + bl;
    int L = lengths[b];
    float pos = ((float)t * (float)(L - 1)) / 9.0f;
    int i0 = (int)pos;
    float f = pos - (float)i0;
    int i1 = min(i0 + 1, L - 1);
    int c0 = words[b * LMAX + i0];
    int c1 = words[b * LMAX + i1];
    const float* p0 = P + c0 * 256 + kc * 32 + khi * 8;
    const float* p1 = P + c1 * 256 + kc * 32 + khi * 8;
    f16x8 r;
#pragma unroll
    for (int j = 0; j < 8; ++j) {
        float v = p0[j] * (1.0f - f) + p1[j] * f;
        v = fmaxf(v, 0.0f);
        r[j] = (f16)v;
    }
    *((f16x8*)seqp + gi) = r;
}

// ---------------------------------------------------------------------------
// K2: fused BiLSTM. 256 blocks (128 fwd + 128 bwd) x 512 thr (8 waves),
// 1 block/CU, 2 waves/SIMD with a 256 reg/lane budget (acc[4][8] = 128 AGPR
// + ~130 arch VGPR). Round-4 structure:
//  - wave tile 64 rows x 128 gate-cols (round-0 permutation, f16x2 combine).
//  - seq tile (32 KB, shared by all 8 waves) DMA'd to LDS one step AHEAD
//    (round-2 win); drained by the per-step barrier, never by a counted wait.
//  - weight stream register-double-buffered at HALF-kc granularity: two
//    groups of 4 B-tiles (bA/bB) alternate -- MFMA on one group while the
//    other group's 4 global loads (4 KB/wave) fly. Same 32 bfrag VGPRs as a
//    flat scheme; compiler emits counted vmcnt(4) waits. This breaks the
//    round-2 load-all/wait-all/mfma-all convoy with ~330-660 cy of cover
//    per wait (vs 84 cy in the failed round-3 LDS ring).
//  - consumption order: h-half (packed kc 8..15) first, then seq half, so
//    the step's seq tile (staged last step) is long-resident when read.
// LDS = 64 KB hbuf + 64 KB sbuf = 128 KB. One barrier per step.
// ---------------------------------------------------------------------------
__global__ __launch_bounds__(512) void lstm_fused(
    const f16* __restrict__ seqp, const f16* __restrict__ Wp,
    const float* __restrict__ bp, f16* __restrict__ hcat) {
    const int dir  = blockIdx.x >> 7;
    const int r0t  = (blockIdx.x & 127) << 2;   // row-tile base, 4 tiles of 16
    const int wave = threadIdx.x >> 6;          // 0..7
    const int lane = threadIdx.x & 63;
    const int l16  = lane & 15;
    const int quad = lane >> 4;

    __shared__ __align__(16) f16 hbuf[2][16384];   // 2 x 32 KB  h state
    __shared__ __align__(16) f16 sbuf[2][16384];   // 2 x 32 KB  seq tiles

    // zero h0 buffer (2048 f16x8 entries, 512 threads -> 4 iters)
    {
        f16x8 z = {(f16)0, (f16)0, (f16)0, (f16)0, (f16)0, (f16)0, (f16)0, (f16)0};
        for (int i = threadIdx.x; i < 2048; i += 512) ((f16x8*)hbuf[0])[i] = z;
    }

    // stage seq tile for t0 into sbuf[0] (4 x 8 KB DMA)
    {
        const int t0 = dir ? 9 : 0;
        const f16* s0 = seqp + (size_t)(t0 * 512 + r0t) * 4096;
#pragma unroll
        for (int r = 0; r < 4; ++r)
            gl_lds16(s0 + r * 4096 + threadIdx.x * 8, &sbuf[0][r * 4096 + wave * 512]);
    }

    // per-lane gate biases: wave owns cols [wave*128, wave*128+128)
    const float* bpd = bp + dir * 1024 + wave * 128;
    float bias_l[8];
#pragma unroll
    for (int nt = 0; nt < 8; ++nt) bias_l[nt] = bpd[nt * 16 + l16];

    // weight base: tile (kc, nt) at Wdl + kc*32768 + nt*512
    const f16* Wdl = Wp + dir * 524288 + wave * 4096 + lane * 8;

    // combine geometry (round-0): lane owns units 2*l16, 2*l16+1
    const int wt0 = ((l16 >> 2) * 16 + quad * 4) * 8 + 2 * (l16 & 3);
    const int tile_lo = (r0t * 16 + dir * 8 + wave) * 512;

    float cst[4][4][2];
#pragma unroll
    for (int m = 0; m < 4; ++m)
#pragma unroll
        for (int q = 0; q < 4; ++q) { cst[m][q][0] = 0.0f; cst[m][q][1] = 0.0f; }

    __syncthreads();   // covers h0 zero + t0 seq DMA (barrier drains vmcnt)

    int cur = 0;
#pragma unroll 1
    for (int step = 0; step < TOUT; ++step) {
        const int t = dir ? (9 - step) : step;
        const f16* hb_r = hbuf[cur] + lane * 8;
        const f16* sb   = sbuf[cur] + lane * 8;
        f16*       hb_w = hbuf[cur ^ 1];

        // prologue weight loads for j=0 (packed kc=8): both halves in flight
        f16x8 bA[4], bB[4];
#pragma unroll
        for (int nt = 0; nt < 4; ++nt)
            bA[nt] = *(const f16x8*)(Wdl + 8 * 32768 + nt * 512);
#pragma unroll
        for (int nt = 0; nt < 4; ++nt)
            bB[nt] = *(const f16x8*)(Wdl + 8 * 32768 + (nt + 4) * 512);

        // seq prefetch for NEXT step (issued after weight loads -> j=0 MFMA's
        // counted wait does not drain the DMA; the step barrier does)
        if (step != 9) {
            const int tn = dir ? (t - 1) : (t + 1);
            const f16* ns = seqp + (size_t)(tn * 512 + r0t) * 4096;
#pragma unroll
            for (int r = 0; r < 4; ++r)
                gl_lds16(ns + r * 4096 + threadIdx.x * 8,
                         &sbuf[cur ^ 1][r * 4096 + wave * 512]);
        }

        f32x4 acc[4][8];
#pragma unroll
        for (int m = 0; m < 4; ++m)
#pragma unroll
            for (int nt = 0; nt < 8; ++nt)
#pragma unroll
                for (int q = 0; q < 4; ++q) acc[m][nt][q] = bias_l[nt];

        // ---- K pipeline: j = 0..15, packed kc = j^8 (h-half first) ----
#pragma unroll 1
        for (int j = 0; j < 16; ++j) {
            const int c = j & 7;
            const f16* ab = (j < 8) ? hb_r : sb;
            f16x8 aA[4];
#pragma unroll
            for (int m = 0; m < 4; ++m)
                aA[m] = *(const f16x8*)(ab + (m * 8 + c) * 512);

            // MFMA half 1 (bA); bB for this j still allowed in flight
            __builtin_amdgcn_s_setprio(1);
#pragma unroll
            for (int m = 0; m < 4; ++m)
#pragma unroll
                for (int nt = 0; nt < 4; ++nt)
                    acc[m][nt] = __builtin_amdgcn_mfma_f32_16x16x32_f16(
                        aA[m], bA[nt], acc[m][nt], 0, 0, 0);
            __builtin_amdgcn_s_setprio(0);

            // issue next j's half-1 loads into bA while bB's MFMA runs
            if (j < 15) {
                const int kcn = (j + 1) ^ 8;
#pragma unroll
                for (int nt = 0; nt < 4; ++nt)
                    bA[nt] = *(const f16x8*)(Wdl + kcn * 32768 + nt * 512);
            }

            // MFMA half 2 (bB)
            __builtin_amdgcn_s_setprio(1);
#pragma unroll
            for (int m = 0; m < 4; ++m)
#pragma unroll
                for (int nt = 0; nt < 4; ++nt)
                    acc[m][nt + 4] = __builtin_amdgcn_mfma_f32_16x16x32_f16(
                        aA[m], bB[nt], acc[m][nt + 4], 0, 0, 0);
            __builtin_amdgcn_s_setprio(0);

            // issue next j's half-2 loads into bB
            if (j < 15) {
                const int kcn = (j + 1) ^ 8;
#pragma unroll
                for (int nt = 0; nt < 4; ++nt)
                    bB[nt] = *(const f16x8*)(Wdl + kcn * 32768 + (nt + 4) * 512);
            }
        }

        // lane-local gate combine; h -> LDS (recurrence) + global hcat.
        // acc[m][nt][q]: row = m*16+quad*4+q; nt = gate*2+us; units 2*l16+us
        f16* hct = hcat + ((size_t)t * 4194304 + tile_lo);
#pragma unroll
        for (int m = 0; m < 4; ++m) {
#pragma unroll
            for (int q = 0; q < 4; ++q) {
                float i0 = acc[m][0][q], i1 = acc[m][1][q];
                float f0 = acc[m][2][q], f1 = acc[m][3][q];
                float g0 = acc[m][4][q], g1 = acc[m][5][q];
                float o0 = acc[m][6][q], o1 = acc[m][7][q];
                float c0 = sigm_(f0) * cst[m][q][0] + sigm_(i0) * tanh_(g0);
                float c1 = sigm_(f1) * cst[m][q][1] + sigm_(i1) * tanh_(g1);
                cst[m][q][0] = c0;
                cst[m][q][1] = c1;
                float h0 = sigm_(o0) * tanh_(c0);
                float h1 = sigm_(o1) * tanh_(c1);
                f16x2 hv = pk_f16(h0, h1);
                int wt = wt0 + q * 8;
                *(f16x2*)&hb_w[(m * 8 + wave) * 512 + wt] = hv;
                *(f16x2*)(hct + m * 8192 + wt) = hv;
            }
        }

        __syncthreads();   // single barrier per step; drains seq DMA
        cur ^= 1;
    }
}

// ---------------------------------------------------------------------------
// K3: out = h_cat(81920x512 f16, frag layout) @ W3p + out_b -> fp32 (B,10,512)
// 1280 blocks x 512 thr; block tile 64 rows x 512 cols; wave: 64x64.
// ---------------------------------------------------------------------------
__global__ __launch_bounds__(512) void out_gemm(
    const f16* __restrict__ hcat, const f16* __restrict__ W3p,
    const float* __restrict__ out_b, float* __restrict__ out) {
    const int mt0  = blockIdx.x << 2;
    const int wave = threadIdx.x >> 6;
    const int lane = threadIdx.x & 63;
    const int l16  = lane & 15;
    const int quad = lane >> 4;
    const int n0   = wave * 64;

    float bias_l[4];
#pragma unroll
    for (int nt = 0; nt < 4; ++nt) bias_l[nt] = out_b[n0 + nt * 16 + l16];

    f32x4 acc[4][4];
#pragma unroll
    for (int m = 0; m < 4; ++m)
#pragma unroll
        for (int nt = 0; nt < 4; ++nt)
#pragma unroll
            for (int q = 0; q < 4; ++q) acc[m][nt][q] = bias_l[nt];

#pragma unroll 2
    for (int kc = 0; kc < 16; ++kc) {
        f16x8 a[4], b[4];
#pragma unroll
        for (int m = 0; m < 4; ++m)
            a[m] = *(const f16x8*)(hcat + ((size_t)((mt0 + m) * 16 + kc) * 512 + lane * 8));
#pragma unroll
        for (int nt = 0; nt < 4; ++nt)
            b[nt] = *(const f16x8*)(W3p + ((kc * 32 + wave * 4 + nt) * 512 + lane * 8));
#pragma unroll
        for (int m = 0; m < 4; ++m)
#pragma unroll
            for (int nt = 0; nt < 4; ++nt)
                acc[m][nt] = __builtin_amdgcn_mfma_f32_16x16x32_f16(a[m], b[nt], acc[m][nt], 0, 0, 0);
    }

#pragma unroll
    for (int m = 0; m < 4; ++m) {
#pragma unroll
        for (int nt = 0; nt < 4; ++nt) {
#pragma unroll
            for (int q = 0; q < 4; ++q) {
                int R = mt0 * 16 + m * 16 + quad * 4 + q;
                int t = R >> 13;
                int b = R & 8191;
                out[(size_t)(b * 10 + t) * 512 + n0 + nt * 16 + l16] = acc[m][nt][q];
            }
        }
    }
}

// ---------------------------------------------------------------------------
extern "C" void kernel_launch(void* const* d_in, const int* in_sizes, int n_in,
                              void* d_out, int out_size, void* d_ws, size_t ws_size,
                              hipStream_t stream) {
    const int*   words   = (const int*)d_in[0];
    const int*   lengths = (const int*)d_in[1];
    const float* tab     = (const float*)d_in[2];
    const float* enc_w   = (const float*)d_in[3];
    const float* enc_b   = (const float*)d_in[4];
    const float* wih_f   = (const float*)d_in[5];
    const float* whh_f   = (const float*)d_in[6];
    const float* bih_f   = (const float*)d_in[7];
    const float* bhh_f   = (const float*)d_in[8];
    const float* wih_b   = (const float*)d_in[9];
    const float* whh_b   = (const float*)d_in[10];
    const float* bih_b   = (const float*)d_in[11];
    const float* bhh_b   = (const float*)d_in[12];
    const float* out_w   = (const float*)d_in[13];
    const float* out_b   = (const float*)d_in[14];
    float* out = (float*)d_out;

    char* ws = (char*)d_ws;
    f16*   Wp   = (f16*)(ws + 0);           //  2 MB
    f16*   W3p  = (f16*)(ws + 2097152);     //  0.5 MB
    float* bp   = (float*)(ws + 2621440);   //  8 KB
    float* P    = (float*)(ws + 2629632);   //  36 KB
    f16*   seqp = (f16*)(ws + 2666496);     //  40 MB
    f16*   hcat = (f16*)(ws + 44609536);    //  80 MB  (total ~122.6 MB)

    pack_w2<<<4096, 256, 0, stream>>>(wih_f, whh_f, wih_b, whh_b, Wp);
    pack_bias<<<8, 256, 0, stream>>>(bih_f, bhh_f, bih_b, bhh_b, bp);
    pack_w3<<<1024, 256, 0, stream>>>(out_w, W3p);
    enc_proj<<<36, 256, 0, stream>>>(tab, enc_w, enc_b, P);
    build_seq<<<10240, 256, 0, stream>>>(words, lengths, P, seqp);
    lstm_fused<<<256, 512, 0, stream>>>(seqp, Wp, bp, hcat);
    out_gemm<<<1280, 512, 0, stream>>>(hcat, W3p, out_b, out);
}